// Round 13
// baseline (783.199 us; speedup 1.0000x reference)
//
#include <hip/hip_runtime.h>

// ---------------------------------------------------------------------------
// LavaNetwork, bit-exact 4-plane i8 MFMA GEMM (mfma_i32_16x16x64_i8).
//   w ~ k*2^-31 (k = rint(w*2^31), residual <= 2^-32), 4 balanced base-256
//   digits -> exact i8 planes, exact i32 sums, exact i64 Horner + f64 bias.
// Round-13: gemm1_static rebalanced for occupancy: 16-m blocks, 32 KB static
// weight LDS (full K=512), 5 blocks/CU via launch_bounds(256,5). Barrier-free
// k-loop retained. Everything else = round-12 (lif1_t register-resident,
// round-9 gemm2, proven preps/expand/lif2).
// Fallback: round-3 proven f16 path if ws too small.
// ---------------------------------------------------------------------------

typedef int i32x4 __attribute__((ext_vector_type(4)));
typedef _Float16 f16x8 __attribute__((ext_vector_type(8)));
typedef _Float16 f16x4 __attribute__((ext_vector_type(4)));
typedef float f32x4 __attribute__((ext_vector_type(4)));

#define GLDS(g, l) __builtin_amdgcn_global_load_lds( \
    (const __attribute__((address_space(1))) void*)(g), \
    (__attribute__((address_space(3))) void*)(l), 16, 0, 0)

#define INV231 4.656612873077392578125e-10   // 2^-31

// ======================= prep =======================

// w (M,K) f32 -> wp [K/64][4][M][64] i8 digit planes; 16-B chunk c of row m
// stored at c ^ ((m>>1)&3)  (proven conflict-free for ds_read_b128).
__global__ __launch_bounds__(256) void prep_w8(const float* __restrict__ A,
                                               signed char* __restrict__ wp,
                                               int M, int K)
{
    long gt = (long)blockIdx.x * 256 + threadIdx.x;
    int kq4 = K >> 2;
    int m = (int)(gt / kq4), kq = (int)(gt % kq4);
    int k0 = kq * 4;
    int kt = k0 >> 6, kin = k0 & 63;
    int cw = ((kin >> 4) ^ (m >> 1)) & 3;
    float4 w = *(const float4*)&A[(long)m * K + k0];
    float wv[4] = {w.x, w.y, w.z, w.w};
    int pack[4] = {0, 0, 0, 0};
#pragma unroll
    for (int e = 0; e < 4; e++) {
        long k64 = (long)rint((double)wv[e] * 2147483648.0);  // * 2^31
#pragma unroll
        for (int j = 0; j < 3; j++) {
            long r = ((k64 + 128) & 255) - 128;   // balanced digit [-128,127]
            pack[j] |= ((int)r & 255) << (e * 8);
            k64 = (k64 - r) >> 8;
        }
        pack[3] |= ((int)k64 & 255) << (e * 8);
    }
#pragma unroll
    for (int p = 0; p < 4; p++)
        *(int*)&wp[(((long)kt * 4 + p) * M + m) * 64 + cw * 16 + (kin & 15)] = pack[p];
}

// x [b][512][1024] f32 -> x8t [b][8][1024][64] i8 (k-tile-major, plain).
__global__ __launch_bounds__(256) void prep_x8(const float* __restrict__ x,
                                               unsigned char* __restrict__ xt)
{
    __shared__ float xs[64][68];
    const int b = blockIdx.z, i0 = blockIdx.y * 64, t0 = blockIdx.x * 64;
    const float* xb = x + ((long)b * 512 + i0) * 1024 + t0;
#pragma unroll
    for (int p = 0; p < 4; p++) {
        int f = threadIdx.x + p * 256;
        int i = f >> 4, t4 = (f & 15) * 4;
        *(float4*)&xs[i][t4] = *(const float4*)&xb[(long)i * 1024 + t4];
    }
    __syncthreads();
    int tt = threadIdx.x >> 2, c = threadIdx.x & 3;
    unsigned char bytes[16];
#pragma unroll
    for (int j = 0; j < 16; j++)
        bytes[j] = (unsigned char)xs[c * 16 + j][tt];
    *(uint4*)&xt[(((long)b * 8 + (i0 >> 6)) * 1024 + t0 + tt) * 64 + c * 16] =
        *(uint4*)bytes;
}

// ======================= layer-1 GEMM: static weights, 16-m blocks ==========
// D[t][M] = acts @ W^T (cur1t). Grid (x=m/16, y=t/128, z=b); x fastest so 128
// blocks share each 64 KB act slab in L2. All K=512 weights for the 16-m
// slice = 32 KB LDS, staged once; k-loop has NO barriers and NO staging.
// 5 blocks/CU (LDS-capped), 5 waves/SIMD.
__global__ __launch_bounds__(256, 5) void gemm1_static(
    const signed char* __restrict__ wp,     // [8][4][M][64] swizzled chunks
    const unsigned char* __restrict__ act,  // [b][8][1024][64] plain
    const float* __restrict__ bias,         // (M)
    float* __restrict__ C,                  // [b][1024][M]
    int M)
{
    __shared__ signed char Ws[8][4][16][64];   // 32 KB

    const int b = blockIdx.z;
    const int m0 = blockIdx.x * 16;
    const int t0 = blockIdx.y * 128;
    const int tid = threadIdx.x, lane = tid & 63, wave = tid >> 6;
    const int wt = t0 + wave * 32;             // wave-private 32-t slice
    const int lm = lane & 15, lq = lane >> 4;
    const int fro = ((lq ^ (lm >> 1)) & 3) * 16;   // proven swizzle read offset
    const int gl_t = lane >> 2, gl_c = (lane & 3) * 16;

    const unsigned char* ab = act + (long)b * 8 * 1024 * 64;
    float* Cb = C + (long)b * 1024 * M;

    // stage ALL weights once: 32 slabs of 1 KB, 8 per wave
    for (int r = wave; r < 32; r += 4) {
        const int kt = r >> 2, p = r & 3;
        const signed char* g =
            wp + (((long)kt * 4 + p) * M + m0 + gl_t) * 64 + gl_c;
        GLDS(g, &Ws[kt][p][0][0]);
    }
    __syncthreads();   // the ONLY barrier

    i32x4 acc[4][2];   // [plane][t-frag]
#pragma unroll
    for (int p = 0; p < 4; p++)
#pragma unroll
        for (int i = 0; i < 2; i++) acc[p][i] = (i32x4)0;

    i32x4 a0 = *(const i32x4*)&ab[((long)(wt + lm)) * 64 + lq * 16];
    i32x4 a1 = *(const i32x4*)&ab[((long)(wt + 16 + lm)) * 64 + lq * 16];

#pragma unroll
    for (int it = 0; it < 8; it++) {
        i32x4 an0, an1;
        if (it < 7) {
            an0 = *(const i32x4*)&ab[((long)(it + 1) * 1024 + wt + lm) * 64 + lq * 16];
            an1 = *(const i32x4*)&ab[((long)(it + 1) * 1024 + wt + 16 + lm) * 64 + lq * 16];
        }
#pragma unroll
        for (int p = 0; p < 4; p++) {
            i32x4 w0 = *(const i32x4*)&Ws[it][p][lm][fro];
            acc[p][0] = __builtin_amdgcn_mfma_i32_16x16x64_i8(a0, w0, acc[p][0], 0, 0, 0);
            acc[p][1] = __builtin_amdgcn_mfma_i32_16x16x64_i8(a1, w0, acc[p][1], 0, 0, 0);
        }
        if (it < 7) { a0 = an0; a1 = an1; }
    }

    // epilogue (round-9-proven TRANS indexing, single m-frag)
    const double bv0 = (double)bias[m0 + lm];
#pragma unroll
    for (int tf = 0; tf < 2; tf++)
#pragma unroll
        for (int r = 0; r < 4; r++) {
            const int trow = wt + tf * 16 + lq * 4 + r;
            long T = acc[3][tf][r];
            T = T * 256 + acc[2][tf][r];
            T = T * 256 + acc[1][tf][r];
            T = T * 256 + acc[0][tf][r];
            Cb[(long)trow * M + m0 + lm] = (float)((double)T * INV231 + bv0);
        }
}

// ======================= layer-2 GEMM (round-9 proven) =======================
template <bool TRANS>
__global__ __launch_bounds__(256, 3) void gemm_i8(
    const signed char* __restrict__ wp,     // [K/64][4][M][64] swizzled
    const unsigned char* __restrict__ act,  // [b][K/64][1024][64] plain
    const float* __restrict__ bias,         // (M)
    float* __restrict__ C,
    int M, int K)
{
    __shared__ signed char Ws[2][4][32][64];   // 16 KB

    const int b = blockIdx.z;
    const int m0 = (TRANS ? blockIdx.x : blockIdx.y) * 32;
    const int t0 = (TRANS ? blockIdx.y : blockIdx.x) * 128;
    const int tid = threadIdx.x, lane = tid & 63, wave = tid >> 6;
    const int wt = t0 + wave * 32;
    const int lm = lane & 15, lq = lane >> 4;
    const int fro = ((lq ^ (lm >> 1)) & 3) * 16;
    const int gl_t = lane >> 2, gl_c = (lane & 3) * 16;
    const int niter = K >> 6;

    const unsigned char* ab = act + (long)b * niter * 1024 * 64;
    const int p0 = wave >> 1, s0 = wave & 1;
    const int p1 = (wave + 4) >> 1, s1 = wave & 1;

    i32x4 acc[4][2][2];
#pragma unroll
    for (int p = 0; p < 4; p++)
#pragma unroll
        for (int i = 0; i < 2; i++)
#pragma unroll
            for (int j = 0; j < 2; j++) acc[p][i][j] = (i32x4)0;

    {
        const signed char* g0 = wp + (((long)p0) * M + m0 + s0 * 16 + gl_t) * 64 + gl_c;
        const signed char* g1 = wp + (((long)p1) * M + m0 + s1 * 16 + gl_t) * 64 + gl_c;
        GLDS(g0, &Ws[0][p0][s0 * 16][0]);
        GLDS(g1, &Ws[0][p1][s1 * 16][0]);
    }
    i32x4 a0 = *(const i32x4*)&ab[((long)(wt + 0 * 16 + lm)) * 64 + lq * 16];
    i32x4 a1 = *(const i32x4*)&ab[((long)(wt + 1 * 16 + lm)) * 64 + lq * 16];
    __syncthreads();

    for (int it = 0; it < niter; it++) {
        const int buf = it & 1;
        const int nx = (it + 1 < niter) ? it + 1 : it;
        if (it + 1 < niter) {
            const long kb = (long)(it + 1) * 4;
            const signed char* g0 =
                wp + ((kb + p0) * M + m0 + s0 * 16 + gl_t) * 64 + gl_c;
            const signed char* g1 =
                wp + ((kb + p1) * M + m0 + s1 * 16 + gl_t) * 64 + gl_c;
            GLDS(g0, &Ws[buf ^ 1][p0][s0 * 16][0]);
            GLDS(g1, &Ws[buf ^ 1][p1][s1 * 16][0]);
        }
        i32x4 an0 = *(const i32x4*)&ab[((long)nx * 1024 + wt + 0 * 16 + lm) * 64 + lq * 16];
        i32x4 an1 = *(const i32x4*)&ab[((long)nx * 1024 + wt + 1 * 16 + lm) * 64 + lq * 16];

#pragma unroll
        for (int p = 0; p < 4; p++) {
            i32x4 w0 = *(const i32x4*)&Ws[buf][p][lm][fro];
            i32x4 w1 = *(const i32x4*)&Ws[buf][p][16 + lm][fro];
            if (TRANS) {
                acc[p][0][0] = __builtin_amdgcn_mfma_i32_16x16x64_i8(a0, w0, acc[p][0][0], 0, 0, 0);
                acc[p][0][1] = __builtin_amdgcn_mfma_i32_16x16x64_i8(a0, w1, acc[p][0][1], 0, 0, 0);
                acc[p][1][0] = __builtin_amdgcn_mfma_i32_16x16x64_i8(a1, w0, acc[p][1][0], 0, 0, 0);
                acc[p][1][1] = __builtin_amdgcn_mfma_i32_16x16x64_i8(a1, w1, acc[p][1][1], 0, 0, 0);
            } else {
                acc[p][0][0] = __builtin_amdgcn_mfma_i32_16x16x64_i8(w0, a0, acc[p][0][0], 0, 0, 0);
                acc[p][0][1] = __builtin_amdgcn_mfma_i32_16x16x64_i8(w0, a1, acc[p][0][1], 0, 0, 0);
                acc[p][1][0] = __builtin_amdgcn_mfma_i32_16x16x64_i8(w1, a0, acc[p][1][0], 0, 0, 0);
                acc[p][1][1] = __builtin_amdgcn_mfma_i32_16x16x64_i8(w1, a1, acc[p][1][1], 0, 0, 0);
            }
        }
        __syncthreads();
        a0 = an0; a1 = an1;
    }

    if (TRANS) {
        double bv[2];
        bv[0] = (double)bias[m0 + lm];
        bv[1] = (double)bias[m0 + 16 + lm];
        float* Cb = C + (long)b * 1024 * M;
#pragma unroll
        for (int tf = 0; tf < 2; tf++)
#pragma unroll
            for (int r = 0; r < 4; r++) {
                const int trow = wt + tf * 16 + lq * 4 + r;
#pragma unroll
                for (int mf = 0; mf < 2; mf++) {
                    long T = acc[3][tf][mf][r];
                    T = T * 256 + acc[2][tf][mf][r];
                    T = T * 256 + acc[1][tf][mf][r];
                    T = T * 256 + acc[0][tf][mf][r];
                    Cb[(long)trow * M + m0 + mf * 16 + lm] =
                        (float)((double)T * INV231 + bv[mf]);
                }
            }
    } else {
        float* Cb = C + (long)b * M * 1024;
#pragma unroll
        for (int mf = 0; mf < 2; mf++)
#pragma unroll
            for (int r = 0; r < 4; r++) {
                const int mrow = m0 + mf * 16 + lq * 4 + r;
                const double bv = (double)bias[mrow];
#pragma unroll
                for (int tf = 0; tf < 2; tf++) {
                    long T = acc[3][mf][tf][r];
                    T = T * 256 + acc[2][mf][tf][r];
                    T = T * 256 + acc[1][mf][tf][r];
                    T = T * 256 + acc[0][mf][tf][r];
                    Cb[(long)mrow * 1024 + wt + tf * 16 + lm] =
                        (float)((double)T * INV231 + bv);
                }
            }
    }
}

// ======================= LIF =======================

// Coalesced thread-per-row scan over cur1t [b][1024][2048] (register-resident
// c[32], constant indices); emits i8 spikes [b][32][1024][64] + masks.
__global__ __launch_bounds__(256) void lif1_t(
    const float* __restrict__ ct,
    unsigned char* __restrict__ spk8,
    unsigned* __restrict__ mask_ws)
{
    const int b = blockIdx.y;
    const int m = blockIdx.x * 256 + threadIdx.x;
    const float* src = ct + (long)b * 1024 * 2048 + m;
    unsigned char* spb = spk8 + (((long)b * 32 + (m >> 6)) * 1024) * 64 + (m & 63);
    unsigned* mw = mask_ws + (long)b * 32 * 2048 + m;
    double v = 0.0;
    for (int tw = 0; tw < 32; tw++) {
        float c[32];
#pragma unroll
        for (int j = 0; j < 32; j++)
            c[j] = src[(long)(tw * 32 + j) * 2048];
        unsigned mword = 0;
#pragma unroll
        for (int j = 0; j < 32; j++) {
            v = 0.95 * v + (double)c[j];
            bool s = v >= 1.0;
            mword |= (s ? 1u : 0u) << j;
            if (s) v = 0.0;
            spb[(long)(tw * 32 + j) * 64] = s ? 1 : 0;
        }
        mw[(long)tw * 2048] = mword;
    }
}

// masks [b][32][2048] -> f32 spikes [b][2048][1024]
__global__ __launch_bounds__(256) void expand_spk(
    const unsigned* __restrict__ mask_ws,
    float* __restrict__ spk1)
{
    __shared__ unsigned msk[8][32];
    const long rowbase = (long)blockIdx.x * 8;
    const int b = (int)(rowbase >> 11), m0 = (int)(rowbase & 2047);
    const int tid = threadIdx.x;
    {
        int w = tid >> 3, r = tid & 7;
        msk[r][w] = mask_ws[((long)b * 32 + w) * 2048 + m0 + r];
    }
    __syncthreads();
    const int r = tid >> 5, l5 = tid & 31;
    float* dst = spk1 + (rowbase + r) * 1024;
    const int sh = (l5 & 7) * 4;
#pragma unroll
    for (int j = 0; j < 8; j++) {
        const int t = l5 * 4 + j * 128;
        const unsigned w = msk[r][(l5 >> 3) + j * 4];
        float4 o;
        o.x = ((w >> sh) & 1u) ? 1.f : 0.f;
        o.y = ((w >> (sh + 1)) & 1u) ? 1.f : 0.f;
        o.z = ((w >> (sh + 2)) & 1u) ? 1.f : 0.f;
        o.w = ((w >> (sh + 3)) & 1u) ? 1.f : 0.f;
        *(float4*)&dst[t] = o;
    }
}

// LDS-chunked LIF for layer 2 (proven round 4)
template <int RPB>
__global__ __launch_bounds__(256) void lif_lds(float* __restrict__ cur)
{
    __shared__ float cs[RPB][36];
    const long rowbase = (long)blockIdx.x * RPB;
    float* base = cur + rowbase * 1024;
    const int tid = threadIdx.x;
    double v = 0.0;
    const int NV = RPB * 32 / 4;
    for (int tc = 0; tc < 1024; tc += 32) {
        for (int f = tid; f < NV; f += 256) {
            int row = f >> 3, t4 = (f & 7) * 4;
            *(float4*)&cs[row][t4] = *(const float4*)&base[(long)row * 1024 + tc + t4];
        }
        __syncthreads();
        if (tid < RPB) {
#pragma unroll
            for (int j = 0; j < 32; j++) {
                v = 0.95 * v + (double)cs[tid][j];
                bool s = v >= 1.0;
                cs[tid][j] = s ? 1.f : 0.f;
                if (s) v = 0.0;
            }
        }
        __syncthreads();
        for (int f = tid; f < NV; f += 256) {
            int row = f >> 3, t4 = (f & 7) * 4;
            *(float4*)&base[(long)row * 1024 + tc + t4] = *(float4*)&cs[row][t4];
        }
        __syncthreads();
    }
}

// ======================= fallback (round 3, proven) =======================

__device__ inline void split3(float w, _Float16& q0, _Float16& q1, _Float16& q2) {
    float p0 = rintf(w * 4096.f) * 2.44140625e-4f;
    float r1 = w - p0;
    float p1s = rintf(r1 * 8388608.f) * 2.44140625e-4f;
    float r2 = r1 - p1s * 4.8828125e-4f;
    float p2s = rintf(r2 * 1.7179869184e10f) * 1.220703125e-4f;
    q0 = (_Float16)p0; q1 = (_Float16)p1s; q2 = (_Float16)p2s;
}

__global__ __launch_bounds__(256) void gemm_f16x3_kernel(
    const float* __restrict__ A, const float* __restrict__ Bmat,
    const float* __restrict__ bias, float* __restrict__ C,
    int M, int N, int K, long sB, long sC)
{
    __shared__ _Float16 As[3][128][40];
    __shared__ _Float16 Bsh[128][40];
    const int batch = blockIdx.z;
    const float* Bp = Bmat + (long)batch * sB;
    float* Cp = C + (long)batch * sC;
    const int m0 = blockIdx.y * 128, n0 = blockIdx.x * 128;
    const int tid = threadIdx.x, lane = tid & 63, wave = tid >> 6;
    const int wrow = (wave >> 1) * 64, wcol = (wave & 1) * 64;
    const int lm = lane & 15, lq = lane >> 4;
    const int a_mo = tid >> 3, a_kc = (tid & 7) * 4;
    const int b_kq = tid >> 5, b_nq = tid & 31;

    f32x4 acc[3][4][4];
#pragma unroll
    for (int p = 0; p < 3; p++)
#pragma unroll
        for (int i = 0; i < 4; i++)
#pragma unroll
            for (int j = 0; j < 4; j++) acc[p][i][j] = (f32x4)0.f;

    for (int k0 = 0; k0 < K; k0 += 32) {
#pragma unroll
        for (int i = 0; i < 4; i++) {
            const int m = i * 32 + a_mo;
            float4 w = *(const float4*)&A[(long)(m0 + m) * K + k0 + a_kc];
            _Float16 a0[4], a1[4], a2[4];
            split3(w.x, a0[0], a1[0], a2[0]);
            split3(w.y, a0[1], a1[1], a2[1]);
            split3(w.z, a0[2], a1[2], a2[2]);
            split3(w.w, a0[3], a1[3], a2[3]);
            *(f16x4*)&As[0][m][a_kc] = (f16x4){a0[0], a0[1], a0[2], a0[3]};
            *(f16x4*)&As[1][m][a_kc] = (f16x4){a1[0], a1[1], a1[2], a1[3]};
            *(f16x4*)&As[2][m][a_kc] = (f16x4){a2[0], a2[1], a2[2], a2[3]};
        }
        {
            float4 r0 = *(const float4*)&Bp[(long)(k0 + b_kq * 4 + 0) * N + n0 + b_nq * 4];
            float4 r1 = *(const float4*)&Bp[(long)(k0 + b_kq * 4 + 1) * N + n0 + b_nq * 4];
            float4 r2 = *(const float4*)&Bp[(long)(k0 + b_kq * 4 + 2) * N + n0 + b_nq * 4];
            float4 r3 = *(const float4*)&Bp[(long)(k0 + b_kq * 4 + 3) * N + n0 + b_nq * 4];
            *(f16x4*)&Bsh[b_nq * 4 + 0][b_kq * 4] =
                (f16x4){(_Float16)r0.x, (_Float16)r1.x, (_Float16)r2.x, (_Float16)r3.x};
            *(f16x4*)&Bsh[b_nq * 4 + 1][b_kq * 4] =
                (f16x4){(_Float16)r0.y, (_Float16)r1.y, (_Float16)r2.y, (_Float16)r3.y};
            *(f16x4*)&Bsh[b_nq * 4 + 2][b_kq * 4] =
                (f16x4){(_Float16)r0.z, (_Float16)r1.z, (_Float16)r2.z, (_Float16)r3.z};
            *(f16x4*)&Bsh[b_nq * 4 + 3][b_kq * 4] =
                (f16x4){(_Float16)r0.w, (_Float16)r1.w, (_Float16)r2.w, (_Float16)r3.w};
        }
        __syncthreads();
        f16x8 bf[4];
#pragma unroll
        for (int j = 0; j < 4; j++)
            bf[j] = *(const f16x8*)&Bsh[wcol + j * 16 + lm][lq * 8];
#pragma unroll
        for (int p = 0; p < 3; p++) {
            f16x8 af[4];
#pragma unroll
            for (int i = 0; i < 4; i++)
                af[i] = *(const f16x8*)&As[p][wrow + i * 16 + lm][lq * 8];
#pragma unroll
            for (int i = 0; i < 4; i++)
#pragma unroll
                for (int j = 0; j < 4; j++)
                    acc[p][i][j] = __builtin_amdgcn_mfma_f32_16x16x32_f16(
                        af[i], bf[j], acc[p][i][j], 0, 0, 0);
        }
        __syncthreads();
    }
#pragma unroll
    for (int i = 0; i < 4; i++)
#pragma unroll
        for (int r = 0; r < 4; r++) {
            const int row = m0 + wrow + i * 16 + lq * 4 + r;
            const double bv = (double)bias[row];
#pragma unroll
            for (int j = 0; j < 4; j++) {
                double s = (double)acc[0][i][j][r]
                         + (double)acc[1][i][j][r] * 4.8828125e-4
                         + (double)acc[2][i][j][r] * 4.76837158203125e-7 + bv;
                Cp[(long)row * N + n0 + wcol + j * 16 + lm] = (float)s;
            }
        }
}

__global__ __launch_bounds__(256) void lif_rows(float* __restrict__ data,
                                                long nrows, int T)
{
    long r = (long)blockIdx.x * blockDim.x + threadIdx.x;
    if (r >= nrows) return;
    float* p = data + r * (long)T;
    double v = 0.0;
    for (int t = 0; t < T; t += 4) {
        float4 c = *(float4*)(p + t);
        float4 s;
        v = 0.95 * v + (double)c.x; s.x = (v >= 1.0) ? 1.f : 0.f; if (v >= 1.0) v = 0.0;
        v = 0.95 * v + (double)c.y; s.y = (v >= 1.0) ? 1.f : 0.f; if (v >= 1.0) v = 0.0;
        v = 0.95 * v + (double)c.z; s.z = (v >= 1.0) ? 1.f : 0.f; if (v >= 1.0) v = 0.0;
        v = 0.95 * v + (double)c.w; s.w = (v >= 1.0) ? 1.f : 0.f; if (v >= 1.0) v = 0.0;
        *(float4*)(p + t) = s;
    }
}

// ======================= launch =======================

extern "C" void kernel_launch(void* const* d_in, const int* in_sizes, int n_in,
                              void* d_out, int out_size, void* d_ws, size_t ws_size,
                              hipStream_t stream)
{
    const float* x  = (const float*)d_in[0];  // (32, 512, 1024)
    const float* w1 = (const float*)d_in[1];  // (2048, 512)
    const float* b1 = (const float*)d_in[2];  // (2048)
    const float* w2 = (const float*)d_in[3];  // (256, 2048)
    const float* b2 = (const float*)d_in[4];  // (256)

    float* out  = (float*)d_out;
    float* spk1 = out;                              // (32, 2048, 1024)
    float* spk2 = out + (long)32 * 2048 * 1024;     // (32, 256, 1024)

    const size_t WP1 = 4194304;        // [8][4][2048][64] i8
    const size_t WP2 = 2097152;        // [32][4][256][64] i8
    const size_t X8T = 16777216;       // [32][8][1024][64] i8
    const size_t SPK = 67108864;       // [32][32][1024][64] i8
    const size_t MSK = 8388608;        // [32][32][2048] u32
    const size_t NEED = WP1 + WP2 + X8T + SPK + MSK;

    if (ws_size >= NEED) {
        char* ws = (char*)d_ws;
        signed char* wp1 = (signed char*)ws;
        signed char* wp2 = (signed char*)(ws + WP1);
        unsigned char* x8t = (unsigned char*)(ws + WP1 + WP2);
        unsigned char* spk8 = (unsigned char*)(ws + WP1 + WP2 + X8T);
        unsigned* mask_ws = (unsigned*)(ws + WP1 + WP2 + X8T + SPK);

        prep_w8<<<1024, 256, 0, stream>>>(w1, wp1, 2048, 512);
        prep_w8<<<512, 256, 0, stream>>>(w2, wp2, 256, 2048);
        prep_x8<<<dim3(16, 8, 32), 256, 0, stream>>>(x, x8t);

        // layer 1: cur1t [b][t][2048], static-weight barrier-free k-loop,
        // 16-m blocks for 5 blocks/CU occupancy, m-fastest grid for L2 reuse
        gemm1_static<<<dim3(128, 8, 32), 256, 0, stream>>>(
            wp1, x8t, b1, spk1, 2048);
        lif1_t<<<dim3(8, 32), 256, 0, stream>>>(spk1, spk8, mask_ws);
        expand_spk<<<8192, 256, 0, stream>>>(mask_ws, spk1);

        // layer 2: cur2 [b][256][1024] direct -> in-place LIF
        gemm_i8<false><<<dim3(8, 8, 32), 256, 0, stream>>>(
            wp2, spk8, b2, spk2, 256, 2048);
        lif_lds<128><<<64, 256, 0, stream>>>(spk2);
    } else {
        gemm_f16x3_kernel<<<dim3(8, 16, 32), 256, 0, stream>>>(
            w1, x, b1, spk1, 2048, 1024, 512, (long)512 * 1024, (long)2048 * 1024);
        lif_rows<<<(65536 + 255) / 256, 256, 0, stream>>>(spk1, 65536, 1024);
        gemm_f16x3_kernel<<<dim3(8, 2, 32), 256, 0, stream>>>(
            w2, spk1, b2, spk2, 256, 1024, 2048, (long)2048 * 1024, (long)256 * 1024);
        lif_rows<<<(8192 + 255) / 256, 256, 0, stream>>>(spk2, 8192, 1024);
    }
}

// Round 14
// 748.567 us; speedup vs baseline: 1.0463x; 1.0463x over previous
//
#include <hip/hip_runtime.h>

// ---------------------------------------------------------------------------
// LavaNetwork, bit-exact 4-plane i8 MFMA GEMM (mfma_i32_16x16x64_i8).
//   w ~ k*2^-31 (k = rint(w*2^31), residual <= 2^-32), 4 balanced base-256
//   digits -> exact i8 planes, exact i32 sums, exact i64 Horner + f64 bias.
// Round-14: gemm1_static wave tile widened to 64t x 16m (4 t-frags): LDS
// reads per MFMA drop 0.5 -> 0.25, turning the kernel MFMA-bound (r13 showed
// the per-CU LDS pipe, not occupancy, was binding at 2 t-frags). Block =
// 256t x 16m, 32 KB static weight LDS, barrier-free k-loop, 4 blocks/CU.
// Everything else = round-13 (proven).
// Fallback: round-3 proven f16 path if ws too small.
// ---------------------------------------------------------------------------

typedef int i32x4 __attribute__((ext_vector_type(4)));
typedef _Float16 f16x8 __attribute__((ext_vector_type(8)));
typedef _Float16 f16x4 __attribute__((ext_vector_type(4)));
typedef float f32x4 __attribute__((ext_vector_type(4)));

#define GLDS(g, l) __builtin_amdgcn_global_load_lds( \
    (const __attribute__((address_space(1))) void*)(g), \
    (__attribute__((address_space(3))) void*)(l), 16, 0, 0)

#define INV231 4.656612873077392578125e-10   // 2^-31

// ======================= prep =======================

// w (M,K) f32 -> wp [K/64][4][M][64] i8 digit planes; 16-B chunk c of row m
// stored at c ^ ((m>>1)&3)  (proven conflict-free for ds_read_b128).
__global__ __launch_bounds__(256) void prep_w8(const float* __restrict__ A,
                                               signed char* __restrict__ wp,
                                               int M, int K)
{
    long gt = (long)blockIdx.x * 256 + threadIdx.x;
    int kq4 = K >> 2;
    int m = (int)(gt / kq4), kq = (int)(gt % kq4);
    int k0 = kq * 4;
    int kt = k0 >> 6, kin = k0 & 63;
    int cw = ((kin >> 4) ^ (m >> 1)) & 3;
    float4 w = *(const float4*)&A[(long)m * K + k0];
    float wv[4] = {w.x, w.y, w.z, w.w};
    int pack[4] = {0, 0, 0, 0};
#pragma unroll
    for (int e = 0; e < 4; e++) {
        long k64 = (long)rint((double)wv[e] * 2147483648.0);  // * 2^31
#pragma unroll
        for (int j = 0; j < 3; j++) {
            long r = ((k64 + 128) & 255) - 128;   // balanced digit [-128,127]
            pack[j] |= ((int)r & 255) << (e * 8);
            k64 = (k64 - r) >> 8;
        }
        pack[3] |= ((int)k64 & 255) << (e * 8);
    }
#pragma unroll
    for (int p = 0; p < 4; p++)
        *(int*)&wp[(((long)kt * 4 + p) * M + m) * 64 + cw * 16 + (kin & 15)] = pack[p];
}

// x [b][512][1024] f32 -> x8t [b][8][1024][64] i8 (k-tile-major, plain).
__global__ __launch_bounds__(256) void prep_x8(const float* __restrict__ x,
                                               unsigned char* __restrict__ xt)
{
    __shared__ float xs[64][68];
    const int b = blockIdx.z, i0 = blockIdx.y * 64, t0 = blockIdx.x * 64;
    const float* xb = x + ((long)b * 512 + i0) * 1024 + t0;
#pragma unroll
    for (int p = 0; p < 4; p++) {
        int f = threadIdx.x + p * 256;
        int i = f >> 4, t4 = (f & 15) * 4;
        *(float4*)&xs[i][t4] = *(const float4*)&xb[(long)i * 1024 + t4];
    }
    __syncthreads();
    int tt = threadIdx.x >> 2, c = threadIdx.x & 3;
    unsigned char bytes[16];
#pragma unroll
    for (int j = 0; j < 16; j++)
        bytes[j] = (unsigned char)xs[c * 16 + j][tt];
    *(uint4*)&xt[(((long)b * 8 + (i0 >> 6)) * 1024 + t0 + tt) * 64 + c * 16] =
        *(uint4*)bytes;
}

// ======================= layer-1 GEMM: static weights, 64t x 16m waves ======
// D[t][M] = acts @ W^T (cur1t). Grid (x=m/16, y=t/256, z=b); x fastest so 128
// blocks share each act slab in L2. All K=512 weights for the 16-m slice =
// 32 KB LDS, staged once; k-loop has NO barriers and NO staging. Each wave
// owns 64 t (4 frags), so each weight-frag ds_read feeds 4 MFMAs.
__global__ __launch_bounds__(256, 4) void gemm1_static(
    const signed char* __restrict__ wp,     // [8][4][M][64] swizzled chunks
    const unsigned char* __restrict__ act,  // [b][8][1024][64] plain
    const float* __restrict__ bias,         // (M)
    float* __restrict__ C,                  // [b][1024][M]
    int M)
{
    __shared__ signed char Ws[8][4][16][64];   // 32 KB

    const int b = blockIdx.z;
    const int m0 = blockIdx.x * 16;
    const int t0 = blockIdx.y * 256;
    const int tid = threadIdx.x, lane = tid & 63, wave = tid >> 6;
    const int wt = t0 + wave * 64;             // wave-private 64-t slice
    const int lm = lane & 15, lq = lane >> 4;
    const int fro = ((lq ^ (lm >> 1)) & 3) * 16;   // proven swizzle read offset
    const int gl_t = lane >> 2, gl_c = (lane & 3) * 16;

    const unsigned char* ab = act + (long)b * 8 * 1024 * 64;
    float* Cb = C + (long)b * 1024 * M;

    // stage ALL weights once: 32 slabs of 1 KB, 8 per wave
    for (int r = wave; r < 32; r += 4) {
        const int kt = r >> 2, p = r & 3;
        const signed char* g =
            wp + (((long)kt * 4 + p) * M + m0 + gl_t) * 64 + gl_c;
        GLDS(g, &Ws[kt][p][0][0]);
    }
    __syncthreads();   // the ONLY barrier

    i32x4 acc[4][4];   // [plane][t-frag]
#pragma unroll
    for (int p = 0; p < 4; p++)
#pragma unroll
        for (int i = 0; i < 4; i++) acc[p][i] = (i32x4)0;

    i32x4 a[4], an[4];
#pragma unroll
    for (int i = 0; i < 4; i++)
        a[i] = *(const i32x4*)&ab[((long)(wt + i * 16 + lm)) * 64 + lq * 16];

#pragma unroll
    for (int it = 0; it < 8; it++) {
        if (it < 7) {
#pragma unroll
            for (int i = 0; i < 4; i++)
                an[i] = *(const i32x4*)&ab[((long)(it + 1) * 1024 + wt + i * 16 + lm) * 64 + lq * 16];
        }
#pragma unroll
        for (int p = 0; p < 4; p++) {
            i32x4 w0 = *(const i32x4*)&Ws[it][p][lm][fro];
            acc[p][0] = __builtin_amdgcn_mfma_i32_16x16x64_i8(a[0], w0, acc[p][0], 0, 0, 0);
            acc[p][1] = __builtin_amdgcn_mfma_i32_16x16x64_i8(a[1], w0, acc[p][1], 0, 0, 0);
            acc[p][2] = __builtin_amdgcn_mfma_i32_16x16x64_i8(a[2], w0, acc[p][2], 0, 0, 0);
            acc[p][3] = __builtin_amdgcn_mfma_i32_16x16x64_i8(a[3], w0, acc[p][3], 0, 0, 0);
        }
        if (it < 7) {
#pragma unroll
            for (int i = 0; i < 4; i++) a[i] = an[i];
        }
    }

    // epilogue (round-9/13-proven TRANS indexing, single m-frag)
    const double bv0 = (double)bias[m0 + lm];
#pragma unroll
    for (int tf = 0; tf < 4; tf++)
#pragma unroll
        for (int r = 0; r < 4; r++) {
            const int trow = wt + tf * 16 + lq * 4 + r;
            long T = acc[3][tf][r];
            T = T * 256 + acc[2][tf][r];
            T = T * 256 + acc[1][tf][r];
            T = T * 256 + acc[0][tf][r];
            Cb[(long)trow * M + m0 + lm] = (float)((double)T * INV231 + bv0);
        }
}

// ======================= layer-2 GEMM (round-9 proven) =======================
template <bool TRANS>
__global__ __launch_bounds__(256, 3) void gemm_i8(
    const signed char* __restrict__ wp,     // [K/64][4][M][64] swizzled
    const unsigned char* __restrict__ act,  // [b][K/64][1024][64] plain
    const float* __restrict__ bias,         // (M)
    float* __restrict__ C,
    int M, int K)
{
    __shared__ signed char Ws[2][4][32][64];   // 16 KB

    const int b = blockIdx.z;
    const int m0 = (TRANS ? blockIdx.x : blockIdx.y) * 32;
    const int t0 = (TRANS ? blockIdx.y : blockIdx.x) * 128;
    const int tid = threadIdx.x, lane = tid & 63, wave = tid >> 6;
    const int wt = t0 + wave * 32;
    const int lm = lane & 15, lq = lane >> 4;
    const int fro = ((lq ^ (lm >> 1)) & 3) * 16;
    const int gl_t = lane >> 2, gl_c = (lane & 3) * 16;
    const int niter = K >> 6;

    const unsigned char* ab = act + (long)b * niter * 1024 * 64;
    const int p0 = wave >> 1, s0 = wave & 1;
    const int p1 = (wave + 4) >> 1, s1 = wave & 1;

    i32x4 acc[4][2][2];
#pragma unroll
    for (int p = 0; p < 4; p++)
#pragma unroll
        for (int i = 0; i < 2; i++)
#pragma unroll
            for (int j = 0; j < 2; j++) acc[p][i][j] = (i32x4)0;

    {
        const signed char* g0 = wp + (((long)p0) * M + m0 + s0 * 16 + gl_t) * 64 + gl_c;
        const signed char* g1 = wp + (((long)p1) * M + m0 + s1 * 16 + gl_t) * 64 + gl_c;
        GLDS(g0, &Ws[0][p0][s0 * 16][0]);
        GLDS(g1, &Ws[0][p1][s1 * 16][0]);
    }
    i32x4 a0 = *(const i32x4*)&ab[((long)(wt + 0 * 16 + lm)) * 64 + lq * 16];
    i32x4 a1 = *(const i32x4*)&ab[((long)(wt + 1 * 16 + lm)) * 64 + lq * 16];
    __syncthreads();

    for (int it = 0; it < niter; it++) {
        const int buf = it & 1;
        const int nx = (it + 1 < niter) ? it + 1 : it;
        if (it + 1 < niter) {
            const long kb = (long)(it + 1) * 4;
            const signed char* g0 =
                wp + ((kb + p0) * M + m0 + s0 * 16 + gl_t) * 64 + gl_c;
            const signed char* g1 =
                wp + ((kb + p1) * M + m0 + s1 * 16 + gl_t) * 64 + gl_c;
            GLDS(g0, &Ws[buf ^ 1][p0][s0 * 16][0]);
            GLDS(g1, &Ws[buf ^ 1][p1][s1 * 16][0]);
        }
        i32x4 an0 = *(const i32x4*)&ab[((long)nx * 1024 + wt + 0 * 16 + lm) * 64 + lq * 16];
        i32x4 an1 = *(const i32x4*)&ab[((long)nx * 1024 + wt + 1 * 16 + lm) * 64 + lq * 16];

#pragma unroll
        for (int p = 0; p < 4; p++) {
            i32x4 w0 = *(const i32x4*)&Ws[buf][p][lm][fro];
            i32x4 w1 = *(const i32x4*)&Ws[buf][p][16 + lm][fro];
            if (TRANS) {
                acc[p][0][0] = __builtin_amdgcn_mfma_i32_16x16x64_i8(a0, w0, acc[p][0][0], 0, 0, 0);
                acc[p][0][1] = __builtin_amdgcn_mfma_i32_16x16x64_i8(a0, w1, acc[p][0][1], 0, 0, 0);
                acc[p][1][0] = __builtin_amdgcn_mfma_i32_16x16x64_i8(a1, w0, acc[p][1][0], 0, 0, 0);
                acc[p][1][1] = __builtin_amdgcn_mfma_i32_16x16x64_i8(a1, w1, acc[p][1][1], 0, 0, 0);
            } else {
                acc[p][0][0] = __builtin_amdgcn_mfma_i32_16x16x64_i8(w0, a0, acc[p][0][0], 0, 0, 0);
                acc[p][0][1] = __builtin_amdgcn_mfma_i32_16x16x64_i8(w0, a1, acc[p][0][1], 0, 0, 0);
                acc[p][1][0] = __builtin_amdgcn_mfma_i32_16x16x64_i8(w1, a0, acc[p][1][0], 0, 0, 0);
                acc[p][1][1] = __builtin_amdgcn_mfma_i32_16x16x64_i8(w1, a1, acc[p][1][1], 0, 0, 0);
            }
        }
        __syncthreads();
        a0 = an0; a1 = an1;
    }

    if (TRANS) {
        double bv[2];
        bv[0] = (double)bias[m0 + lm];
        bv[1] = (double)bias[m0 + 16 + lm];
        float* Cb = C + (long)b * 1024 * M;
#pragma unroll
        for (int tf = 0; tf < 2; tf++)
#pragma unroll
            for (int r = 0; r < 4; r++) {
                const int trow = wt + tf * 16 + lq * 4 + r;
#pragma unroll
                for (int mf = 0; mf < 2; mf++) {
                    long T = acc[3][tf][mf][r];
                    T = T * 256 + acc[2][tf][mf][r];
                    T = T * 256 + acc[1][tf][mf][r];
                    T = T * 256 + acc[0][tf][mf][r];
                    Cb[(long)trow * M + m0 + mf * 16 + lm] =
                        (float)((double)T * INV231 + bv[mf]);
                }
            }
    } else {
        float* Cb = C + (long)b * M * 1024;
#pragma unroll
        for (int mf = 0; mf < 2; mf++)
#pragma unroll
            for (int r = 0; r < 4; r++) {
                const int mrow = m0 + mf * 16 + lq * 4 + r;
                const double bv = (double)bias[mrow];
#pragma unroll
                for (int tf = 0; tf < 2; tf++) {
                    long T = acc[3][mf][tf][r];
                    T = T * 256 + acc[2][mf][tf][r];
                    T = T * 256 + acc[1][mf][tf][r];
                    T = T * 256 + acc[0][mf][tf][r];
                    Cb[(long)mrow * 1024 + wt + tf * 16 + lm] =
                        (float)((double)T * INV231 + bv);
                }
            }
    }
}

// ======================= LIF =======================

// Coalesced thread-per-row scan over cur1t [b][1024][2048] (register-resident
// c[32], constant indices); emits i8 spikes [b][32][1024][64] + masks.
__global__ __launch_bounds__(256) void lif1_t(
    const float* __restrict__ ct,
    unsigned char* __restrict__ spk8,
    unsigned* __restrict__ mask_ws)
{
    const int b = blockIdx.y;
    const int m = blockIdx.x * 256 + threadIdx.x;
    const float* src = ct + (long)b * 1024 * 2048 + m;
    unsigned char* spb = spk8 + (((long)b * 32 + (m >> 6)) * 1024) * 64 + (m & 63);
    unsigned* mw = mask_ws + (long)b * 32 * 2048 + m;
    double v = 0.0;
    for (int tw = 0; tw < 32; tw++) {
        float c[32];
#pragma unroll
        for (int j = 0; j < 32; j++)
            c[j] = src[(long)(tw * 32 + j) * 2048];
        unsigned mword = 0;
#pragma unroll
        for (int j = 0; j < 32; j++) {
            v = 0.95 * v + (double)c[j];
            bool s = v >= 1.0;
            mword |= (s ? 1u : 0u) << j;
            if (s) v = 0.0;
            spb[(long)(tw * 32 + j) * 64] = s ? 1 : 0;
        }
        mw[(long)tw * 2048] = mword;
    }
}

// masks [b][32][2048] -> f32 spikes [b][2048][1024]
__global__ __launch_bounds__(256) void expand_spk(
    const unsigned* __restrict__ mask_ws,
    float* __restrict__ spk1)
{
    __shared__ unsigned msk[8][32];
    const long rowbase = (long)blockIdx.x * 8;
    const int b = (int)(rowbase >> 11), m0 = (int)(rowbase & 2047);
    const int tid = threadIdx.x;
    {
        int w = tid >> 3, r = tid & 7;
        msk[r][w] = mask_ws[((long)b * 32 + w) * 2048 + m0 + r];
    }
    __syncthreads();
    const int r = tid >> 5, l5 = tid & 31;
    float* dst = spk1 + (rowbase + r) * 1024;
    const int sh = (l5 & 7) * 4;
#pragma unroll
    for (int j = 0; j < 8; j++) {
        const int t = l5 * 4 + j * 128;
        const unsigned w = msk[r][(l5 >> 3) + j * 4];
        float4 o;
        o.x = ((w >> sh) & 1u) ? 1.f : 0.f;
        o.y = ((w >> (sh + 1)) & 1u) ? 1.f : 0.f;
        o.z = ((w >> (sh + 2)) & 1u) ? 1.f : 0.f;
        o.w = ((w >> (sh + 3)) & 1u) ? 1.f : 0.f;
        *(float4*)&dst[t] = o;
    }
}

// LDS-chunked LIF for layer 2 (proven round 4)
template <int RPB>
__global__ __launch_bounds__(256) void lif_lds(float* __restrict__ cur)
{
    __shared__ float cs[RPB][36];
    const long rowbase = (long)blockIdx.x * RPB;
    float* base = cur + rowbase * 1024;
    const int tid = threadIdx.x;
    double v = 0.0;
    const int NV = RPB * 32 / 4;
    for (int tc = 0; tc < 1024; tc += 32) {
        for (int f = tid; f < NV; f += 256) {
            int row = f >> 3, t4 = (f & 7) * 4;
            *(float4*)&cs[row][t4] = *(const float4*)&base[(long)row * 1024 + tc + t4];
        }
        __syncthreads();
        if (tid < RPB) {
#pragma unroll
            for (int j = 0; j < 32; j++) {
                v = 0.95 * v + (double)cs[tid][j];
                bool s = v >= 1.0;
                cs[tid][j] = s ? 1.f : 0.f;
                if (s) v = 0.0;
            }
        }
        __syncthreads();
        for (int f = tid; f < NV; f += 256) {
            int row = f >> 3, t4 = (f & 7) * 4;
            *(float4*)&base[(long)row * 1024 + tc + t4] = *(float4*)&cs[row][t4];
        }
        __syncthreads();
    }
}

// ======================= fallback (round 3, proven) =======================

__device__ inline void split3(float w, _Float16& q0, _Float16& q1, _Float16& q2) {
    float p0 = rintf(w * 4096.f) * 2.44140625e-4f;
    float r1 = w - p0;
    float p1s = rintf(r1 * 8388608.f) * 2.44140625e-4f;
    float r2 = r1 - p1s * 4.8828125e-4f;
    float p2s = rintf(r2 * 1.7179869184e10f) * 1.220703125e-4f;
    q0 = (_Float16)p0; q1 = (_Float16)p1s; q2 = (_Float16)p2s;
}

__global__ __launch_bounds__(256) void gemm_f16x3_kernel(
    const float* __restrict__ A, const float* __restrict__ Bmat,
    const float* __restrict__ bias, float* __restrict__ C,
    int M, int N, int K, long sB, long sC)
{
    __shared__ _Float16 As[3][128][40];
    __shared__ _Float16 Bsh[128][40];
    const int batch = blockIdx.z;
    const float* Bp = Bmat + (long)batch * sB;
    float* Cp = C + (long)batch * sC;
    const int m0 = blockIdx.y * 128, n0 = blockIdx.x * 128;
    const int tid = threadIdx.x, lane = tid & 63, wave = tid >> 6;
    const int wrow = (wave >> 1) * 64, wcol = (wave & 1) * 64;
    const int lm = lane & 15, lq = lane >> 4;
    const int a_mo = tid >> 3, a_kc = (tid & 7) * 4;
    const int b_kq = tid >> 5, b_nq = tid & 31;

    f32x4 acc[3][4][4];
#pragma unroll
    for (int p = 0; p < 3; p++)
#pragma unroll
        for (int i = 0; i < 4; i++)
#pragma unroll
            for (int j = 0; j < 4; j++) acc[p][i][j] = (f32x4)0.f;

    for (int k0 = 0; k0 < K; k0 += 32) {
#pragma unroll
        for (int i = 0; i < 4; i++) {
            const int m = i * 32 + a_mo;
            float4 w = *(const float4*)&A[(long)(m0 + m) * K + k0 + a_kc];
            _Float16 a0[4], a1[4], a2[4];
            split3(w.x, a0[0], a1[0], a2[0]);
            split3(w.y, a0[1], a1[1], a2[1]);
            split3(w.z, a0[2], a1[2], a2[2]);
            split3(w.w, a0[3], a1[3], a2[3]);
            *(f16x4*)&As[0][m][a_kc] = (f16x4){a0[0], a0[1], a0[2], a0[3]};
            *(f16x4*)&As[1][m][a_kc] = (f16x4){a1[0], a1[1], a1[2], a1[3]};
            *(f16x4*)&As[2][m][a_kc] = (f16x4){a2[0], a2[1], a2[2], a2[3]};
        }
        {
            float4 r0 = *(const float4*)&Bp[(long)(k0 + b_kq * 4 + 0) * N + n0 + b_nq * 4];
            float4 r1 = *(const float4*)&Bp[(long)(k0 + b_kq * 4 + 1) * N + n0 + b_nq * 4];
            float4 r2 = *(const float4*)&Bp[(long)(k0 + b_kq * 4 + 2) * N + n0 + b_nq * 4];
            float4 r3 = *(const float4*)&Bp[(long)(k0 + b_kq * 4 + 3) * N + n0 + b_nq * 4];
            *(f16x4*)&Bsh[b_nq * 4 + 0][b_kq * 4] =
                (f16x4){(_Float16)r0.x, (_Float16)r1.x, (_Float16)r2.x, (_Float16)r3.x};
            *(f16x4*)&Bsh[b_nq * 4 + 1][b_kq * 4] =
                (f16x4){(_Float16)r0.y, (_Float16)r1.y, (_Float16)r2.y, (_Float16)r3.y};
            *(f16x4*)&Bsh[b_nq * 4 + 2][b_kq * 4] =
                (f16x4){(_Float16)r0.z, (_Float16)r1.z, (_Float16)r2.z, (_Float16)r3.z};
            *(f16x4*)&Bsh[b_nq * 4 + 3][b_kq * 4] =
                (f16x4){(_Float16)r0.w, (_Float16)r1.w, (_Float16)r2.w, (_Float16)r3.w};
        }
        __syncthreads();
        f16x8 bf[4];
#pragma unroll
        for (int j = 0; j < 4; j++)
            bf[j] = *(const f16x8*)&Bsh[wcol + j * 16 + lm][lq * 8];
#pragma unroll
        for (int p = 0; p < 3; p++) {
            f16x8 af[4];
#pragma unroll
            for (int i = 0; i < 4; i++)
                af[i] = *(const f16x8*)&As[p][wrow + i * 16 + lm][lq * 8];
#pragma unroll
            for (int i = 0; i < 4; i++)
#pragma unroll
                for (int j = 0; j < 4; j++)
                    acc[p][i][j] = __builtin_amdgcn_mfma_f32_16x16x32_f16(
                        af[i], bf[j], acc[p][i][j], 0, 0, 0);
        }
        __syncthreads();
    }
#pragma unroll
    for (int i = 0; i < 4; i++)
#pragma unroll
        for (int r = 0; r < 4; r++) {
            const int row = m0 + wrow + i * 16 + lq * 4 + r;
            const double bv = (double)bias[row];
#pragma unroll
            for (int j = 0; j < 4; j++) {
                double s = (double)acc[0][i][j][r]
                         + (double)acc[1][i][j][r] * 4.8828125e-4
                         + (double)acc[2][i][j][r] * 4.76837158203125e-7 + bv;
                Cp[(long)row * N + n0 + wcol + j * 16 + lm] = (float)s;
            }
        }
}

__global__ __launch_bounds__(256) void lif_rows(float* __restrict__ data,
                                                long nrows, int T)
{
    long r = (long)blockIdx.x * blockDim.x + threadIdx.x;
    if (r >= nrows) return;
    float* p = data + r * (long)T;
    double v = 0.0;
    for (int t = 0; t < T; t += 4) {
        float4 c = *(float4*)(p + t);
        float4 s;
        v = 0.95 * v + (double)c.x; s.x = (v >= 1.0) ? 1.f : 0.f; if (v >= 1.0) v = 0.0;
        v = 0.95 * v + (double)c.y; s.y = (v >= 1.0) ? 1.f : 0.f; if (v >= 1.0) v = 0.0;
        v = 0.95 * v + (double)c.z; s.z = (v >= 1.0) ? 1.f : 0.f; if (v >= 1.0) v = 0.0;
        v = 0.95 * v + (double)c.w; s.w = (v >= 1.0) ? 1.f : 0.f; if (v >= 1.0) v = 0.0;
        *(float4*)(p + t) = s;
    }
}

// ======================= launch =======================

extern "C" void kernel_launch(void* const* d_in, const int* in_sizes, int n_in,
                              void* d_out, int out_size, void* d_ws, size_t ws_size,
                              hipStream_t stream)
{
    const float* x  = (const float*)d_in[0];  // (32, 512, 1024)
    const float* w1 = (const float*)d_in[1];  // (2048, 512)
    const float* b1 = (const float*)d_in[2];  // (2048)
    const float* w2 = (const float*)d_in[3];  // (256, 2048)
    const float* b2 = (const float*)d_in[4];  // (256)

    float* out  = (float*)d_out;
    float* spk1 = out;                              // (32, 2048, 1024)
    float* spk2 = out + (long)32 * 2048 * 1024;     // (32, 256, 1024)

    const size_t WP1 = 4194304;        // [8][4][2048][64] i8
    const size_t WP2 = 2097152;        // [32][4][256][64] i8
    const size_t X8T = 16777216;       // [32][8][1024][64] i8
    const size_t SPK = 67108864;       // [32][32][1024][64] i8
    const size_t MSK = 8388608;        // [32][32][2048] u32
    const size_t NEED = WP1 + WP2 + X8T + SPK + MSK;

    if (ws_size >= NEED) {
        char* ws = (char*)d_ws;
        signed char* wp1 = (signed char*)ws;
        signed char* wp2 = (signed char*)(ws + WP1);
        unsigned char* x8t = (unsigned char*)(ws + WP1 + WP2);
        unsigned char* spk8 = (unsigned char*)(ws + WP1 + WP2 + X8T);
        unsigned* mask_ws = (unsigned*)(ws + WP1 + WP2 + X8T + SPK);

        prep_w8<<<1024, 256, 0, stream>>>(w1, wp1, 2048, 512);
        prep_w8<<<512, 256, 0, stream>>>(w2, wp2, 256, 2048);
        prep_x8<<<dim3(16, 8, 32), 256, 0, stream>>>(x, x8t);

        // layer 1: cur1t [b][t][2048], static-weight barrier-free k-loop,
        // 64t x 16m wave tiles (0.25 LDS reads per MFMA), m-fastest grid
        gemm1_static<<<dim3(128, 4, 32), 256, 0, stream>>>(
            wp1, x8t, b1, spk1, 2048);
        lif1_t<<<dim3(8, 32), 256, 0, stream>>>(spk1, spk8, mask_ws);
        expand_spk<<<8192, 256, 0, stream>>>(mask_ws, spk1);

        // layer 2: cur2 [b][256][1024] direct -> in-place LIF
        gemm_i8<false><<<dim3(8, 8, 32), 256, 0, stream>>>(
            wp2, spk8, b2, spk2, 256, 2048);
        lif_lds<128><<<64, 256, 0, stream>>>(spk2);
    } else {
        gemm_f16x3_kernel<<<dim3(8, 16, 32), 256, 0, stream>>>(
            w1, x, b1, spk1, 2048, 1024, 512, (long)512 * 1024, (long)2048 * 1024);
        lif_rows<<<(65536 + 255) / 256, 256, 0, stream>>>(spk1, 65536, 1024);
        gemm_f16x3_kernel<<<dim3(8, 2, 32), 256, 0, stream>>>(
            w2, spk1, b2, spk2, 256, 1024, 2048, (long)2048 * 1024, (long)256 * 1024);
        lif_rows<<<(8192 + 255) / 256, 256, 0, stream>>>(spk2, 8192, 1024);
    }
}